// Round 20
// baseline (98.377 us; speedup 1.0000x reference)
//
#include <hip/hip_runtime.h>

#define N_PTS 32768
#define BATCH 16
#define PIO2F 1.5707963705062866f

// ---------------- types / helpers ----------------
typedef __attribute__((ext_vector_type(8))) _Float16 half8;
typedef __attribute__((ext_vector_type(4))) _Float16 half4;
typedef __attribute__((ext_vector_type(4))) float f32x4;

__device__ __forceinline__ float silu_f(float v) {
    return v * __builtin_amdgcn_rcpf(1.0f + __expf(-v));
}

__device__ __forceinline__ float wave_sum(float v) {
    #pragma unroll
    for (int off = 1; off < 64; off <<= 1) v += __shfl_xor(v, off, 64);
    return v;
}

// Free compile-time fence: makes intra-wave cross-lane LDS handoff defined
// (R11 lesson: without it the scheduler reorders ds_write vs cross-lane ds_read).
__device__ __forceinline__ void lds_fence() {
    asm volatile("" ::: "memory");
#if __has_builtin(__builtin_amdgcn_wave_barrier)
    __builtin_amdgcn_wave_barrier();
#else
    __builtin_amdgcn_sched_barrier(0);
#endif
    asm volatile("" ::: "memory");
}

__device__ __forceinline__ f32x4 mfma16h(half8 a, half8 b, f32x4 c) {
    return __builtin_amdgcn_mfma_f32_16x16x32_f16(a, b, c, 0, 0, 0);
}

__device__ __forceinline__ half8 h8zero() {
    half8 z;
    #pragma unroll
    for (int r = 0; r < 8; ++r) z[r] = (_Float16)0.0f;
    return z;
}

// ---------------- kernel 1: hyper-weights wv (latent einsum + LN) ----------------
__global__ void wv_kernel(
    const float* __restrict__ latent,
    const float* __restrict__ pw0, const float* __restrict__ pb0,
    const float* __restrict__ lnw0, const float* __restrict__ lnb0,
    const float* __restrict__ pw1, const float* __restrict__ pb1,
    const float* __restrict__ lnw1, const float* __restrict__ lnb1,
    const float* __restrict__ pw2, const float* __restrict__ pb2,
    const float* __restrict__ lnw2, const float* __restrict__ lnb2,
    const float* __restrict__ pw3, const float* __restrict__ pb3,
    const float* __restrict__ lnw3, const float* __restrict__ lnb3,
    float* __restrict__ wvb) {
    int blk = blockIdx.x;
    int l = blk >> 8;
    int rest = blk & 255;
    int b = rest >> 4, o = rest & 15;
    int c = threadIdx.x;

    const float *pw, *pb, *lnw, *lnb;
    float* outp;
    int ch;
    switch (l) {
        case 0:  pw = pw0; pb = pb0; lnw = lnw0; lnb = lnb0; outp = wvb;                 ch = 62; break;
        case 1:  pw = pw1; pb = pb1; lnw = lnw1; lnb = lnb1; outp = wvb + 15872;         ch = 16; break;
        case 2:  pw = pw2; pb = pb2; lnw = lnw2; lnb = lnb2; outp = wvb + 15872 + 4096;  ch = 16; break;
        default: pw = pw3; pb = pb3; lnw = lnw3; lnb = lnb3; outp = wvb + 15872 + 8192;  ch = 16; break;
    }
    const float* lat = latent + ((size_t)(b * 64 + l * 16 + o)) * 64;
    float dot = 0.f;
    if (c < ch) {
        const float* pr = pw + ((size_t)(o * ch + c)) * 64;
        #pragma unroll
        for (int d0 = 0; d0 < 64; d0++) dot += lat[d0] * pr[d0];
    }
    float act = (c < ch) ? dot : 0.f;
    float mu = wave_sum(act) * (1.0f / ch);
    float diff = (c < ch) ? (dot - mu) : 0.f;
    float var = wave_sum(diff * diff) * (1.0f / ch);
    float norm = diff * rsqrtf(var + 1e-5f);
    if (c < ch) outp[(size_t)(b * 16 + o) * ch + c] = norm * lnw[c] + lnb[c] + pb[o * ch + c];
}

// ---------------- kernel 1b: posenc precompute, single-f16 in frag-chunk layout ----
__global__ __launch_bounds__(256) void posenc_pre(
    const float* __restrict__ xg, _Float16* __restrict__ peh) {
    int p = blockIdx.x * 256 + threadIdx.x;
    float x0 = xg[2 * p], x1 = xg[2 * p + 1];
    size_t pbs = (size_t)(p >> 4) * 1024 + (size_t)(p & 15) * 8;
    #pragma unroll
    for (int c = 0; c < 8; ++c) {
        half8 hv;
        #pragma unroll
        for (int j = 0; j < 8; ++j) {
            float v;
            if (c < 4) {
                int f = 8 * c + j;
                int idx2 = f - 2;
                int s = idx2 >> 1;
                float sc = __uint_as_float((unsigned)(127 + s) << 23);
                float xa = (idx2 & 1) ? x1 : x0;
                v = sinf(xa * sc);
                if (f == 0) v = x0;
                if (f == 1) v = x1;
            } else {
                int t = 8 * (c - 4) + j;
                int s = t >> 1;
                float sc = __uint_as_float((unsigned)(127 + s) << 23);
                float xa = (t & 1) ? x1 : x0;
                v = sinf(fmaf(xa, sc, PIO2F));
                if (t >= 30) v = 0.f;
            }
            hv[j] = (_Float16)v;
        }
        *(half8*)(peh + pbs + c * 128) = hv;
    }
}

// ---------------- LDS layout (bytes), total 52864 -> 3 blocks/CU ----------------
#define BOUNCE_OFF  0            // f16 8 waves x 2 x [16][40]   20480
#define W2H_OFF     20480        // f16 [100][104]     20800  (cols 100..103 = 0)
#define W1H_OFF     41280        // f16 [112][24]       5376  (rows 100..111 = 0)
#define WV0H_OFF    46656        // f16 [16][72]        2304  (cols 62..71 = 0)
#define WVH_OFF     48960        // f16 [3][16][24]     2304
#define B1_OFF      51264        // f32 [112]            448
#define B2_OFF      51712        // f32 [112]            448
#define W3_OFF      52160        // f32 [112]            448  (100..111 = 0)
#define MB_LDS_OFF  52608        // f32 [4][16]          256
#define LDS_TOTAL   52864

// ---------------- kernel 2: full per-point pipeline on MFMA, 2-pt ILP ----------------
// launch_bounds(512,6): HARD VGPR cap ~84 so posenc prefetch regs cannot push
// past the 6-waves/SIMD (3 blocks/CU) threshold (R18 failure mode).
template <bool PRE>
__global__ __launch_bounds__(512, 6) void mfma_kernel(
    const float* __restrict__ xg,
    const _Float16* __restrict__ peh,
    const float* __restrict__ wvb,
    const float* __restrict__ mb0, const float* __restrict__ mb1,
    const float* __restrict__ mb2, const float* __restrict__ mb3,
    const float* __restrict__ w1, const float* __restrict__ b1,
    const float* __restrict__ w2, const float* __restrict__ b2,
    const float* __restrict__ w3, const float* __restrict__ b3,
    float* __restrict__ out) {
    extern __shared__ char smem[];
    _Float16* lds_bounce = (_Float16*)(smem + BOUNCE_OFF);
    _Float16* lds_w2h    = (_Float16*)(smem + W2H_OFF);
    _Float16* lds_w1h    = (_Float16*)(smem + W1H_OFF);
    _Float16* lds_wv0h   = (_Float16*)(smem + WV0H_OFF);
    _Float16* lds_wvh    = (_Float16*)(smem + WVH_OFF);
    float*    lds_b1     = (float*)(smem + B1_OFF);
    float*    lds_b2     = (float*)(smem + B2_OFF);
    float*    lds_w3     = (float*)(smem + W3_OFF);
    float*    lds_mb     = (float*)(smem + MB_LDS_OFF);

    const int b  = blockIdx.x >> 6;
    const int p0 = (blockIdx.x & 63) * 512;

    // ---- stage weights ----
    for (int idx = threadIdx.x; idx < 100 * 104; idx += 512) {
        int o = idx / 104, k = idx - o * 104;
        lds_w2h[idx] = (_Float16)((k < 100) ? w2[o * 100 + k] : 0.f);
    }
    for (int idx = threadIdx.x; idx < 112 * 24; idx += 512) {
        int o = idx / 24, k = idx - o * 24;
        lds_w1h[idx] = (_Float16)((o < 100 && k < 16) ? w1[o * 16 + k] : 0.f);
    }
    const float* wv0g = wvb + b * 992;                 // [16][62]
    for (int idx = threadIdx.x; idx < 16 * 72; idx += 512) {
        int o = idx / 72, k = idx - o * 72;
        lds_wv0h[idx] = (_Float16)((k < 62) ? wv0g[o * 62 + k] : 0.f);
    }
    const float* wv1g = wvb + 15872 + b * 256;
    const float* wv2g = wvb + 15872 + 4096 + b * 256;
    const float* wv3g = wvb + 15872 + 8192 + b * 256;
    for (int idx = threadIdx.x; idx < 3 * 16 * 24; idx += 512) {
        int li = idx / 384, rest = idx - li * 384;
        int o = rest / 24, k = rest - o * 24;
        const float* src = (li == 0) ? wv1g : (li == 1) ? wv2g : wv3g;
        lds_wvh[idx] = (_Float16)((k < 16) ? src[o * 16 + k] : 0.f);
    }
    if (threadIdx.x < 112) {
        int o = threadIdx.x;
        lds_b1[o] = (o < 100) ? b1[o] : 0.f;
        lds_b2[o] = (o < 100) ? b2[o] : 0.f;
        lds_w3[o] = (o < 100) ? w3[o] : 0.f;
    }
    if (threadIdx.x >= 128 && threadIdx.x < 192) {
        int t = threadIdx.x - 128;
        int li = t >> 4, o = t & 15;
        const float* mbp = (li == 0) ? mb0 : (li == 1) ? mb1 : (li == 2) ? mb2 : mb3;
        lds_mb[t] = mbp[o];
    }
    __syncthreads();

    const int l    = threadIdx.x & 63;
    const int w    = threadIdx.x >> 6;
    const int lrow = l & 15;   // point-col (B) / A M-row
    const int lkg  = l >> 4;   // k-group
    _Float16* bwA = lds_bounce + w * 1280;         // region A
    _Float16* bwB = bwA + 640;                     // region B
    const int pbase = w * 64;
    const float b3v = b3[0];
    const int ptg0 = (p0 + pbase) >> 4;
    const bool kmask = (lkg >= 2);

    // ---- the full per-pair pipeline (2-pt ILP), inlined twice ----
    auto pipe = [&](half8 pb0A, half8 pb1A, half8 pb0B, half8 pb1B,
                    int pcolA, int pcolB) {
        // layer 0: K=64, shared A-operand
        f32x4 accA = *(const f32x4*)(lds_mb + lkg * 4);
        f32x4 accB = accA;
        {
            half8 a0 = *(const half8*)(lds_wv0h + lrow * 72 + lkg * 8);
            accA = mfma16h(a0, pb0A, accA);
            accB = mfma16h(a0, pb0B, accB);
            a0 = *(const half8*)(lds_wv0h + lrow * 72 + 32 + lkg * 8);
            accA = mfma16h(a0, pb1A, accA);
            accB = mfma16h(a0, pb1B, accB);
        }

        // layers 1..3: K=16 real; A-frag cndmask'd for lkg>=2
        #pragma unroll
        for (int li = 0; li < 3; ++li) {
            half4 hvA, hvB;
            #pragma unroll
            for (int r = 0; r < 4; ++r) {
                hvA[r] = (_Float16)silu_f(accA[r]);
                hvB[r] = (_Float16)silu_f(accB[r]);
            }
            lds_fence();
            *(half4*)(bwA + lrow * 40 + lkg * 4) = hvA;
            *(half4*)(bwB + lrow * 40 + lkg * 4) = hvB;
            lds_fence();
            half8 fA = *(const half8*)(bwA + lrow * 40 + (lkg & 1) * 8);
            half8 fB = *(const half8*)(bwB + lrow * 40 + (lkg & 1) * 8);
            f32x4 bias = *(const f32x4*)(lds_mb + (li + 1) * 16 + lkg * 4);
            half8 ah = *(const half8*)(lds_wvh + (li * 16 + lrow) * 24 + (lkg & 1) * 8);
            if (kmask) ah = h8zero();
            accA = mfma16h(ah, fA, bias);
            accB = mfma16h(ah, fB, bias);
        }
        // hb
        {
            half4 hvA, hvB;
            #pragma unroll
            for (int r = 0; r < 4; ++r) {
                hvA[r] = (_Float16)silu_f(accA[r]);
                hvB[r] = (_Float16)silu_f(accB[r]);
            }
            lds_fence();
            *(half4*)(bwA + lrow * 40 + lkg * 4) = hvA;
            *(half4*)(bwB + lrow * 40 + lkg * 4) = hvB;
            lds_fence();
        }
        half8 hbfA = *(const half8*)(bwA + lrow * 40 + (lkg & 1) * 8);
        half8 hbfB = *(const half8*)(bwB + lrow * 40 + (lkg & 1) * 8);

        // w1 interleaved with w2 per k-slice
        f32x4 a2A[7], a2B[7];
        #pragma unroll
        for (int f2 = 0; f2 < 7; ++f2) {
            f32x4 bias = *(const f32x4*)(lds_b2 + f2 * 16 + lkg * 4);
            a2A[f2] = bias;
            a2B[f2] = bias;
        }
        #pragma unroll
        for (int ks = 0; ks < 4; ++ks) {
            lds_fence();                                   // prev h2 read -> these writes
            #pragma unroll
            for (int lf = 0; lf < 2; ++lf) {
                const int fmt = 2 * ks + lf;
                if (fmt < 7) {
                    f32x4 bias = *(const f32x4*)(lds_b1 + fmt * 16 + lkg * 4);
                    half8 ah = *(const half8*)(lds_w1h + (fmt * 16 + lrow) * 24 + (lkg & 1) * 8);
                    if (kmask) ah = h8zero();
                    f32x4 a1A = mfma16h(ah, hbfA, bias);
                    f32x4 a1B = mfma16h(ah, hbfB, bias);
                    half4 hvA, hvB;
                    #pragma unroll
                    for (int r = 0; r < 4; ++r) {
                        hvA[r] = (_Float16)silu_f(a1A[r]);
                        hvB[r] = (_Float16)silu_f(a1B[r]);
                    }
                    *(half4*)(bwA + lrow * 40 + lf * 16 + lkg * 4) = hvA;
                    *(half4*)(bwB + lrow * 40 + lf * 16 + lkg * 4) = hvB;
                } else {
                    half4 hz;
                    #pragma unroll
                    for (int r = 0; r < 4; ++r) hz[r] = (_Float16)0.0f;
                    *(half4*)(bwA + lrow * 40 + lf * 16 + lkg * 4) = hz;
                    *(half4*)(bwB + lrow * 40 + lf * 16 + lkg * 4) = hz;
                }
            }
            lds_fence();                                   // writes -> cross-lane read
            half8 h2fA = *(const half8*)(bwA + lrow * 40 + lkg * 8);
            half8 h2fB = *(const half8*)(bwB + lrow * 40 + lkg * 8);
            const int kb = ks * 32 + lkg * 8;
            const int kba = (ks == 3) ? ((kb > 96) ? 96 : kb) : kb;
            __builtin_amdgcn_s_setprio(1);
            #pragma unroll
            for (int f2 = 0; f2 < 7; ++f2) {
                int arow = f2 * 16 + lrow;
                if (f2 == 6) arow = (arow > 99) ? 99 : arow;
                half8 ah = *(const half8*)(lds_w2h + arow * 104 + kba);
                a2A[f2] = mfma16h(ah, h2fA, a2A[f2]);
                a2B[f2] = mfma16h(ah, h2fB, a2B[f2]);
            }
            __builtin_amdgcn_s_setprio(0);
        }

        // fused silu/w3 epilogue + cross-lane-group reduce, both chains
        float outA = 0.f, outB = 0.f;
        #pragma unroll
        for (int f2 = 0; f2 < 7; ++f2) {
            f32x4 w3v = *(const f32x4*)(lds_w3 + f2 * 16 + lkg * 4);
            #pragma unroll
            for (int r = 0; r < 4; ++r) {
                outA = fmaf(silu_f(a2A[f2][r]), w3v[r], outA);
                outB = fmaf(silu_f(a2B[f2][r]), w3v[r], outB);
            }
        }
        outA += __shfl_xor(outA, 16, 64);
        outA += __shfl_xor(outA, 32, 64);
        outB += __shfl_xor(outB, 16, 64);
        outB += __shfl_xor(outB, 32, 64);
        if (l < 16) {
            out[(size_t)b * N_PTS + pcolA] = outA + b3v;
            out[(size_t)b * N_PTS + pcolB] = outB + b3v;
        }
    };

    const int pA0 = p0 + pbase + lrow;
    if (PRE) {
        // issue ALL 8 posenc frag loads upfront: pair-2's loads stay in
        // flight through pair-1's entire body (R19 was serialized per pair).
        size_t base0 = (size_t)ptg0 * 1024 + (size_t)lkg * 128 + (size_t)lrow * 8;
        half8 f00 = *(const half8*)(peh + base0);
        half8 f01 = *(const half8*)(peh + base0 + 512);
        half8 f10 = *(const half8*)(peh + base0 + 1024);
        half8 f11 = *(const half8*)(peh + base0 + 1536);
        half8 f20 = *(const half8*)(peh + base0 + 2048);
        half8 f21 = *(const half8*)(peh + base0 + 2560);
        half8 f30 = *(const half8*)(peh + base0 + 3072);
        half8 f31 = *(const half8*)(peh + base0 + 3584);
        pipe(f00, f01, f10, f11, pA0, pA0 + 16);
        pipe(f20, f21, f30, f31, pA0 + 32, pA0 + 48);
    } else {
        #pragma unroll 1
        for (int it = 0; it < 2; ++it) {
            half8 fr[4];
            #pragma unroll
            for (int ch = 0; ch < 2; ++ch) {
                const int pc = pA0 + it * 32 + ch * 16;
                const float x0 = xg[2 * pc], x1 = xg[2 * pc + 1];
                half8 t0, t1;
                #pragma unroll
                for (int j = 0; j < 8; ++j) {
                    int idx2 = 8 * lkg + j - 2;
                    int s = idx2 >> 1;
                    float sc = __uint_as_float((unsigned)(127 + s) << 23);
                    float xa = (idx2 & 1) ? x1 : x0;
                    float v = sinf(xa * sc);
                    if (lkg == 0 && j == 0) v = x0;
                    if (lkg == 0 && j == 1) v = x1;
                    t0[j] = (_Float16)v;
                }
                #pragma unroll
                for (int j = 0; j < 8; ++j) {
                    int t = 8 * lkg + j;
                    int s = t >> 1;
                    float sc = __uint_as_float((unsigned)(127 + s) << 23);
                    float xa = (t & 1) ? x1 : x0;
                    float v = sinf(fmaf(xa, sc, PIO2F));
                    if (t >= 30) v = 0.f;
                    t1[j] = (_Float16)v;
                }
                fr[ch * 2] = t0;
                fr[ch * 2 + 1] = t1;
            }
            pipe(fr[0], fr[1], fr[2], fr[3], pA0 + it * 32, pA0 + it * 32 + 16);
        }
    }
}

// ---------------- launcher ----------------
extern "C" void kernel_launch(void* const* d_in, const int* in_sizes, int n_in,
                              void* d_out, int out_size, void* d_ws, size_t ws_size,
                              hipStream_t stream) {
    const float* x = (const float*)d_in[0];
    const float* latent = (const float*)d_in[1];
    const float *pw[4], *pb[4], *lnw[4], *lnb[4], *mb[4];
    for (int l = 0; l < 4; l++) {
        pw[l]  = (const float*)d_in[2 + 5 * l];
        pb[l]  = (const float*)d_in[3 + 5 * l];
        lnw[l] = (const float*)d_in[4 + 5 * l];
        lnb[l] = (const float*)d_in[5 + 5 * l];
        mb[l]  = (const float*)d_in[6 + 5 * l];
    }
    const float* w1 = (const float*)d_in[22];
    const float* b1 = (const float*)d_in[23];
    const float* w2 = (const float*)d_in[24];
    const float* b2 = (const float*)d_in[25];
    const float* w3 = (const float*)d_in[26];
    const float* b3 = (const float*)d_in[27];

    float* wvb = (float*)d_ws;                            // 28160 f32 = 112640 B
    _Float16* peh = (_Float16*)((char*)d_ws + 112640);    // 4 MB
    const size_t WS_NEED = 112640 + (size_t)N_PTS * 64 * sizeof(_Float16);
    bool pre = ws_size >= WS_NEED;

    wv_kernel<<<1024, 64, 0, stream>>>(latent,
        pw[0], pb[0], lnw[0], lnb[0],
        pw[1], pb[1], lnw[1], lnb[1],
        pw[2], pb[2], lnw[2], lnb[2],
        pw[3], pb[3], lnw[3], lnb[3],
        wvb);

    if (pre) {
        posenc_pre<<<N_PTS / 256, 256, 0, stream>>>(x, peh);
        hipFuncSetAttribute((const void*)mfma_kernel<true>,
                            hipFuncAttributeMaxDynamicSharedMemorySize, LDS_TOTAL);
        mfma_kernel<true><<<BATCH * (N_PTS / 512), 512, LDS_TOTAL, stream>>>(
            x, peh, wvb, mb[0], mb[1], mb[2], mb[3],
            w1, b1, w2, b2, w3, b3, (float*)d_out);
    } else {
        hipFuncSetAttribute((const void*)mfma_kernel<false>,
                            hipFuncAttributeMaxDynamicSharedMemorySize, LDS_TOTAL);
        mfma_kernel<false><<<BATCH * (N_PTS / 512), 512, LDS_TOTAL, stream>>>(
            x, peh, wvb, mb[0], mb[1], mb[2], mb[3],
            w1, b1, w2, b2, w3, b3, (float*)d_out);
    }
}

// Round 21
// 74.327 us; speedup vs baseline: 1.3236x; 1.3236x over previous
//
#include <hip/hip_runtime.h>

#define N_PTS 32768
#define BATCH 16
#define PIO2F 1.5707963705062866f

// ---------------- types / helpers ----------------
typedef __attribute__((ext_vector_type(8))) _Float16 half8;
typedef __attribute__((ext_vector_type(4))) _Float16 half4;
typedef __attribute__((ext_vector_type(4))) float f32x4;

__device__ __forceinline__ float silu_f(float v) {
    return v * __builtin_amdgcn_rcpf(1.0f + __expf(-v));
}

__device__ __forceinline__ float wave_sum(float v) {
    #pragma unroll
    for (int off = 1; off < 64; off <<= 1) v += __shfl_xor(v, off, 64);
    return v;
}

// Free compile-time fence: makes intra-wave cross-lane LDS handoff defined
// (R11 lesson: without it the scheduler reorders ds_write vs cross-lane ds_read).
__device__ __forceinline__ void lds_fence() {
    asm volatile("" ::: "memory");
#if __has_builtin(__builtin_amdgcn_wave_barrier)
    __builtin_amdgcn_wave_barrier();
#else
    __builtin_amdgcn_sched_barrier(0);
#endif
    asm volatile("" ::: "memory");
}

__device__ __forceinline__ f32x4 mfma16h(half8 a, half8 b, f32x4 c) {
    return __builtin_amdgcn_mfma_f32_16x16x32_f16(a, b, c, 0, 0, 0);
}

__device__ __forceinline__ half8 h8zero() {
    half8 z;
    #pragma unroll
    for (int r = 0; r < 8; ++r) z[r] = (_Float16)0.0f;
    return z;
}

// ---------------- kernel 1: hyper-weights wv (latent einsum + LN) ----------------
__global__ void wv_kernel(
    const float* __restrict__ latent,
    const float* __restrict__ pw0, const float* __restrict__ pb0,
    const float* __restrict__ lnw0, const float* __restrict__ lnb0,
    const float* __restrict__ pw1, const float* __restrict__ pb1,
    const float* __restrict__ lnw1, const float* __restrict__ lnb1,
    const float* __restrict__ pw2, const float* __restrict__ pb2,
    const float* __restrict__ lnw2, const float* __restrict__ lnb2,
    const float* __restrict__ pw3, const float* __restrict__ pb3,
    const float* __restrict__ lnw3, const float* __restrict__ lnb3,
    float* __restrict__ wvb) {
    int blk = blockIdx.x;
    int l = blk >> 8;
    int rest = blk & 255;
    int b = rest >> 4, o = rest & 15;
    int c = threadIdx.x;

    const float *pw, *pb, *lnw, *lnb;
    float* outp;
    int ch;
    switch (l) {
        case 0:  pw = pw0; pb = pb0; lnw = lnw0; lnb = lnb0; outp = wvb;                 ch = 62; break;
        case 1:  pw = pw1; pb = pb1; lnw = lnw1; lnb = lnb1; outp = wvb + 15872;         ch = 16; break;
        case 2:  pw = pw2; pb = pb2; lnw = lnw2; lnb = lnb2; outp = wvb + 15872 + 4096;  ch = 16; break;
        default: pw = pw3; pb = pb3; lnw = lnw3; lnb = lnb3; outp = wvb + 15872 + 8192;  ch = 16; break;
    }
    const float* lat = latent + ((size_t)(b * 64 + l * 16 + o)) * 64;
    float dot = 0.f;
    if (c < ch) {
        const float* pr = pw + ((size_t)(o * ch + c)) * 64;
        #pragma unroll
        for (int d0 = 0; d0 < 64; d0++) dot += lat[d0] * pr[d0];
    }
    float act = (c < ch) ? dot : 0.f;
    float mu = wave_sum(act) * (1.0f / ch);
    float diff = (c < ch) ? (dot - mu) : 0.f;
    float var = wave_sum(diff * diff) * (1.0f / ch);
    float norm = diff * rsqrtf(var + 1e-5f);
    if (c < ch) outp[(size_t)(b * 16 + o) * ch + c] = norm * lnw[c] + lnb[c] + pb[o * ch + c];
}

// ---------------- kernel 1b: posenc precompute, single-f16 in frag-chunk layout ----
__global__ __launch_bounds__(256) void posenc_pre(
    const float* __restrict__ xg, _Float16* __restrict__ peh) {
    int p = blockIdx.x * 256 + threadIdx.x;
    float x0 = xg[2 * p], x1 = xg[2 * p + 1];
    size_t pbs = (size_t)(p >> 4) * 1024 + (size_t)(p & 15) * 8;
    #pragma unroll
    for (int c = 0; c < 8; ++c) {
        half8 hv;
        #pragma unroll
        for (int j = 0; j < 8; ++j) {
            float v;
            if (c < 4) {
                int f = 8 * c + j;
                int idx2 = f - 2;
                int s = idx2 >> 1;
                float sc = __uint_as_float((unsigned)(127 + s) << 23);
                float xa = (idx2 & 1) ? x1 : x0;
                v = sinf(xa * sc);
                if (f == 0) v = x0;
                if (f == 1) v = x1;
            } else {
                int t = 8 * (c - 4) + j;
                int s = t >> 1;
                float sc = __uint_as_float((unsigned)(127 + s) << 23);
                float xa = (t & 1) ? x1 : x0;
                v = sinf(fmaf(xa, sc, PIO2F));
                if (t >= 30) v = 0.f;
            }
            hv[j] = (_Float16)v;
        }
        *(half8*)(peh + pbs + c * 128) = hv;
    }
}

// ---------------- LDS layout (bytes), total 52864 -> 3 blocks/CU ----------------
#define BOUNCE_OFF  0            // f16 8 waves x 2 x [16][40]   20480
#define W2H_OFF     20480        // f16 [100][104]     20800  (cols 100..103 = 0)
#define W1H_OFF     41280        // f16 [112][24]       5376  (rows 100..111 = 0)
#define WV0H_OFF    46656        // f16 [16][72]        2304  (cols 62..71 = 0)
#define WVH_OFF     48960        // f16 [3][16][24]     2304
#define B1_OFF      51264        // f32 [112]            448
#define B2_OFF      51712        // f32 [112]            448
#define W3_OFF      52160        // f32 [112]            448  (100..111 = 0)
#define MB_LDS_OFF  52608        // f32 [4][16]          256
#define LDS_TOTAL   52864

// ---------------- kernel 2: full per-point pipeline on MFMA, 2-pt ILP ----------------
// launch_bounds(512,2): R20 showed (512,6) pins VGPR to 40 -> catastrophic
// spill; (512,2) leaves the allocator free (it picks ~60 -> 3 blocks/CU fit).
template <bool PRE>
__global__ __launch_bounds__(512, 2) void mfma_kernel(
    const float* __restrict__ xg,
    const _Float16* __restrict__ peh,
    const float* __restrict__ wvb,
    const float* __restrict__ mb0, const float* __restrict__ mb1,
    const float* __restrict__ mb2, const float* __restrict__ mb3,
    const float* __restrict__ w1, const float* __restrict__ b1,
    const float* __restrict__ w2, const float* __restrict__ b2,
    const float* __restrict__ w3, const float* __restrict__ b3,
    float* __restrict__ out) {
    extern __shared__ char smem[];
    _Float16* lds_bounce = (_Float16*)(smem + BOUNCE_OFF);
    _Float16* lds_w2h    = (_Float16*)(smem + W2H_OFF);
    _Float16* lds_w1h    = (_Float16*)(smem + W1H_OFF);
    _Float16* lds_wv0h   = (_Float16*)(smem + WV0H_OFF);
    _Float16* lds_wvh    = (_Float16*)(smem + WVH_OFF);
    float*    lds_b1     = (float*)(smem + B1_OFF);
    float*    lds_b2     = (float*)(smem + B2_OFF);
    float*    lds_w3     = (float*)(smem + W3_OFF);
    float*    lds_mb     = (float*)(smem + MB_LDS_OFF);

    const int b  = blockIdx.x >> 6;
    const int p0 = (blockIdx.x & 63) * 512;

    // ---- stage weights ----
    for (int idx = threadIdx.x; idx < 100 * 104; idx += 512) {
        int o = idx / 104, k = idx - o * 104;
        lds_w2h[idx] = (_Float16)((k < 100) ? w2[o * 100 + k] : 0.f);
    }
    for (int idx = threadIdx.x; idx < 112 * 24; idx += 512) {
        int o = idx / 24, k = idx - o * 24;
        lds_w1h[idx] = (_Float16)((o < 100 && k < 16) ? w1[o * 16 + k] : 0.f);
    }
    const float* wv0g = wvb + b * 992;                 // [16][62]
    for (int idx = threadIdx.x; idx < 16 * 72; idx += 512) {
        int o = idx / 72, k = idx - o * 72;
        lds_wv0h[idx] = (_Float16)((k < 62) ? wv0g[o * 62 + k] : 0.f);
    }
    const float* wv1g = wvb + 15872 + b * 256;
    const float* wv2g = wvb + 15872 + 4096 + b * 256;
    const float* wv3g = wvb + 15872 + 8192 + b * 256;
    for (int idx = threadIdx.x; idx < 3 * 16 * 24; idx += 512) {
        int li = idx / 384, rest = idx - li * 384;
        int o = rest / 24, k = rest - o * 24;
        const float* src = (li == 0) ? wv1g : (li == 1) ? wv2g : wv3g;
        lds_wvh[idx] = (_Float16)((k < 16) ? src[o * 16 + k] : 0.f);
    }
    if (threadIdx.x < 112) {
        int o = threadIdx.x;
        lds_b1[o] = (o < 100) ? b1[o] : 0.f;
        lds_b2[o] = (o < 100) ? b2[o] : 0.f;
        lds_w3[o] = (o < 100) ? w3[o] : 0.f;
    }
    if (threadIdx.x >= 128 && threadIdx.x < 192) {
        int t = threadIdx.x - 128;
        int li = t >> 4, o = t & 15;
        const float* mbp = (li == 0) ? mb0 : (li == 1) ? mb1 : (li == 2) ? mb2 : mb3;
        lds_mb[t] = mbp[o];
    }
    __syncthreads();

    const int l    = threadIdx.x & 63;
    const int w    = threadIdx.x >> 6;
    const int lrow = l & 15;   // point-col (B) / A M-row
    const int lkg  = l >> 4;   // k-group
    _Float16* bwA = lds_bounce + w * 1280;         // region A
    _Float16* bwB = bwA + 640;                     // region B
    const int pbase = w * 64;
    const float b3v = b3[0];
    const int ptg0 = (p0 + pbase) >> 4;
    const bool kmask = (lkg >= 2);

    #pragma unroll 1
    for (int it = 0; it < 2; ++it) {
        const int ptA = it * 2, ptB = ptA + 1;
        const int pcolA = p0 + pbase + ptA * 16 + lrow;
        const int pcolB = pcolA + 16;

        // ---- posenc B-frags, both chains ----
        half8 pb0A, pb1A, pb0B, pb1B;
        if (PRE) {
            size_t baseA = (size_t)(ptg0 + ptA) * 1024 + (size_t)lkg * 128 + (size_t)lrow * 8;
            pb0A = *(const half8*)(peh + baseA);
            pb1A = *(const half8*)(peh + baseA + 512);
            pb0B = *(const half8*)(peh + baseA + 1024);
            pb1B = *(const half8*)(peh + baseA + 1536);
        } else {
            #pragma unroll
            for (int ch = 0; ch < 2; ++ch) {
                const int pc = ch ? pcolB : pcolA;
                const float x0 = xg[2 * pc], x1 = xg[2 * pc + 1];
                half8 t0, t1;
                #pragma unroll
                for (int j = 0; j < 8; ++j) {
                    int idx2 = 8 * lkg + j - 2;
                    int s = idx2 >> 1;
                    float sc = __uint_as_float((unsigned)(127 + s) << 23);
                    float xa = (idx2 & 1) ? x1 : x0;
                    float v = sinf(xa * sc);
                    if (lkg == 0 && j == 0) v = x0;
                    if (lkg == 0 && j == 1) v = x1;
                    t0[j] = (_Float16)v;
                }
                #pragma unroll
                for (int j = 0; j < 8; ++j) {
                    int t = 8 * lkg + j;
                    int s = t >> 1;
                    float sc = __uint_as_float((unsigned)(127 + s) << 23);
                    float xa = (t & 1) ? x1 : x0;
                    float v = sinf(fmaf(xa, sc, PIO2F));
                    if (t >= 30) v = 0.f;
                    t1[j] = (_Float16)v;
                }
                if (ch) { pb0B = t0; pb1B = t1; } else { pb0A = t0; pb1A = t1; }
            }
        }

        // ---- layer 0: K=64, shared A-operand ----
        f32x4 accA = *(const f32x4*)(lds_mb + lkg * 4);
        f32x4 accB = accA;
        {
            half8 a0 = *(const half8*)(lds_wv0h + lrow * 72 + lkg * 8);
            accA = mfma16h(a0, pb0A, accA);
            accB = mfma16h(a0, pb0B, accB);
            a0 = *(const half8*)(lds_wv0h + lrow * 72 + 32 + lkg * 8);
            accA = mfma16h(a0, pb1A, accA);
            accB = mfma16h(a0, pb1B, accB);
        }

        // ---- layers 1..3: K=16 real; A-frag cndmask'd for lkg>=2 ----
        #pragma unroll
        for (int li = 0; li < 3; ++li) {
            half4 hvA, hvB;
            #pragma unroll
            for (int r = 0; r < 4; ++r) {
                hvA[r] = (_Float16)silu_f(accA[r]);
                hvB[r] = (_Float16)silu_f(accB[r]);
            }
            lds_fence();
            *(half4*)(bwA + lrow * 40 + lkg * 4) = hvA;
            *(half4*)(bwB + lrow * 40 + lkg * 4) = hvB;
            lds_fence();
            half8 fA = *(const half8*)(bwA + lrow * 40 + (lkg & 1) * 8);
            half8 fB = *(const half8*)(bwB + lrow * 40 + (lkg & 1) * 8);
            f32x4 bias = *(const f32x4*)(lds_mb + (li + 1) * 16 + lkg * 4);
            half8 ah = *(const half8*)(lds_wvh + (li * 16 + lrow) * 24 + (lkg & 1) * 8);
            if (kmask) ah = h8zero();
            accA = mfma16h(ah, fA, bias);
            accB = mfma16h(ah, fB, bias);
        }
        // hb
        {
            half4 hvA, hvB;
            #pragma unroll
            for (int r = 0; r < 4; ++r) {
                hvA[r] = (_Float16)silu_f(accA[r]);
                hvB[r] = (_Float16)silu_f(accB[r]);
            }
            lds_fence();
            *(half4*)(bwA + lrow * 40 + lkg * 4) = hvA;
            *(half4*)(bwB + lrow * 40 + lkg * 4) = hvB;
            lds_fence();
        }
        half8 hbfA = *(const half8*)(bwA + lrow * 40 + (lkg & 1) * 8);
        half8 hbfB = *(const half8*)(bwB + lrow * 40 + (lkg & 1) * 8);

        // ---- w1 interleaved with w2 per k-slice ----
        f32x4 a2A[7], a2B[7];
        #pragma unroll
        for (int f2 = 0; f2 < 7; ++f2) {
            f32x4 bias = *(const f32x4*)(lds_b2 + f2 * 16 + lkg * 4);
            a2A[f2] = bias;
            a2B[f2] = bias;
        }
        #pragma unroll
        for (int ks = 0; ks < 4; ++ks) {
            lds_fence();                                   // prev h2 read -> these writes
            #pragma unroll
            for (int lf = 0; lf < 2; ++lf) {
                const int fmt = 2 * ks + lf;
                if (fmt < 7) {
                    f32x4 bias = *(const f32x4*)(lds_b1 + fmt * 16 + lkg * 4);
                    half8 ah = *(const half8*)(lds_w1h + (fmt * 16 + lrow) * 24 + (lkg & 1) * 8);
                    if (kmask) ah = h8zero();
                    f32x4 a1A = mfma16h(ah, hbfA, bias);
                    f32x4 a1B = mfma16h(ah, hbfB, bias);
                    half4 hvA, hvB;
                    #pragma unroll
                    for (int r = 0; r < 4; ++r) {
                        hvA[r] = (_Float16)silu_f(a1A[r]);
                        hvB[r] = (_Float16)silu_f(a1B[r]);
                    }
                    *(half4*)(bwA + lrow * 40 + lf * 16 + lkg * 4) = hvA;
                    *(half4*)(bwB + lrow * 40 + lf * 16 + lkg * 4) = hvB;
                } else {
                    half4 hz;
                    #pragma unroll
                    for (int r = 0; r < 4; ++r) hz[r] = (_Float16)0.0f;
                    *(half4*)(bwA + lrow * 40 + lf * 16 + lkg * 4) = hz;
                    *(half4*)(bwB + lrow * 40 + lf * 16 + lkg * 4) = hz;
                }
            }
            lds_fence();                                   // writes -> cross-lane read
            half8 h2fA = *(const half8*)(bwA + lrow * 40 + lkg * 8);
            half8 h2fB = *(const half8*)(bwB + lrow * 40 + lkg * 8);
            const int kb = ks * 32 + lkg * 8;
            const int kba = (ks == 3) ? ((kb > 96) ? 96 : kb) : kb;
            __builtin_amdgcn_s_setprio(1);
            #pragma unroll
            for (int f2 = 0; f2 < 7; ++f2) {
                // f2==6: A rows 100..111 don't exist; clamp to row 99. The
                // garbage lands in C rows (out-feats) 100..111, which the
                // epilogue multiplies by lds_w3[100..111] == 0.
                int arow = f2 * 16 + lrow;
                if (f2 == 6) arow = (arow > 99) ? 99 : arow;
                half8 ah = *(const half8*)(lds_w2h + arow * 104 + kba);
                a2A[f2] = mfma16h(ah, h2fA, a2A[f2]);
                a2B[f2] = mfma16h(ah, h2fB, a2B[f2]);
            }
            __builtin_amdgcn_s_setprio(0);
        }

        // ---- fused silu/w3 epilogue + cross-lane-group reduce, both chains ----
        float outA = 0.f, outB = 0.f;
        #pragma unroll
        for (int f2 = 0; f2 < 7; ++f2) {
            f32x4 w3v = *(const f32x4*)(lds_w3 + f2 * 16 + lkg * 4);
            #pragma unroll
            for (int r = 0; r < 4; ++r) {
                outA = fmaf(silu_f(a2A[f2][r]), w3v[r], outA);
                outB = fmaf(silu_f(a2B[f2][r]), w3v[r], outB);
            }
        }
        outA += __shfl_xor(outA, 16, 64);
        outA += __shfl_xor(outA, 32, 64);
        outB += __shfl_xor(outB, 16, 64);
        outB += __shfl_xor(outB, 32, 64);
        if (l < 16) {
            out[(size_t)b * N_PTS + pcolA] = outA + b3v;
            out[(size_t)b * N_PTS + pcolB] = outB + b3v;
        }
    }
}

// ---------------- launcher ----------------
extern "C" void kernel_launch(void* const* d_in, const int* in_sizes, int n_in,
                              void* d_out, int out_size, void* d_ws, size_t ws_size,
                              hipStream_t stream) {
    const float* x = (const float*)d_in[0];
    const float* latent = (const float*)d_in[1];
    const float *pw[4], *pb[4], *lnw[4], *lnb[4], *mb[4];
    for (int l = 0; l < 4; l++) {
        pw[l]  = (const float*)d_in[2 + 5 * l];
        pb[l]  = (const float*)d_in[3 + 5 * l];
        lnw[l] = (const float*)d_in[4 + 5 * l];
        lnb[l] = (const float*)d_in[5 + 5 * l];
        mb[l]  = (const float*)d_in[6 + 5 * l];
    }
    const float* w1 = (const float*)d_in[22];
    const float* b1 = (const float*)d_in[23];
    const float* w2 = (const float*)d_in[24];
    const float* b2 = (const float*)d_in[25];
    const float* w3 = (const float*)d_in[26];
    const float* b3 = (const float*)d_in[27];

    float* wvb = (float*)d_ws;                            // 28160 f32 = 112640 B
    _Float16* peh = (_Float16*)((char*)d_ws + 112640);    // 4 MB
    const size_t WS_NEED = 112640 + (size_t)N_PTS * 64 * sizeof(_Float16);
    bool pre = ws_size >= WS_NEED;

    wv_kernel<<<1024, 64, 0, stream>>>(latent,
        pw[0], pb[0], lnw[0], lnb[0],
        pw[1], pb[1], lnw[1], lnb[1],
        pw[2], pb[2], lnw[2], lnb[2],
        pw[3], pb[3], lnw[3], lnb[3],
        wvb);

    if (pre) {
        posenc_pre<<<N_PTS / 256, 256, 0, stream>>>(x, peh);
        hipFuncSetAttribute((const void*)mfma_kernel<true>,
                            hipFuncAttributeMaxDynamicSharedMemorySize, LDS_TOTAL);
        mfma_kernel<true><<<BATCH * (N_PTS / 512), 512, LDS_TOTAL, stream>>>(
            x, peh, wvb, mb[0], mb[1], mb[2], mb[3],
            w1, b1, w2, b2, w3, b3, (float*)d_out);
    } else {
        hipFuncSetAttribute((const void*)mfma_kernel<false>,
                            hipFuncAttributeMaxDynamicSharedMemorySize, LDS_TOTAL);
        mfma_kernel<false><<<BATCH * (N_PTS / 512), 512, LDS_TOTAL, stream>>>(
            x, peh, wvb, mb[0], mb[1], mb[2], mb[3],
            w1, b1, w2, b2, w3, b3, (float*)d_out);
    }
}